// Round 7
// baseline (199.534 us; speedup 1.0000x reference)
//
#include <hip/hip_runtime.h>
#include <cstdint>

typedef unsigned short u16;
typedef unsigned int u32;
typedef __attribute__((ext_vector_type(8))) short short8;   // 8 x bf16 bits
typedef __attribute__((ext_vector_type(4))) float f32x4;
typedef __attribute__((ext_vector_type(4))) unsigned short u16x4;
typedef __attribute__((ext_vector_type(4))) u32 u32x4;
typedef __attribute__((ext_vector_type(2))) u32 u32x2;

#define S_ 4096
#define SD 2048

__device__ __forceinline__ u16 f2bf(float f) {
  union { float f; u32 u; } v; v.f = f;
  u32 r = v.u + 0x7fffu + ((v.u >> 16) & 1u);
  return (u16)(r >> 16);
}
#if __has_builtin(__builtin_amdgcn_cvt_pk_bf16_f32)
__device__ __forceinline__ u32 pkbf(float a, float b) {
  auto r = __builtin_amdgcn_cvt_pk_bf16_f32(a, b);
  u32 o; __builtin_memcpy(&o, &r, 4); return o;
}
#else
__device__ __forceinline__ u32 pkbf(float a, float b) {
  union { float f; u32 u; } ua, ub; ua.f = a; ub.f = b;
  return __builtin_amdgcn_perm(ub.u + 0x8000u, ua.u + 0x8000u, 0x07060302u);
}
#endif
// raw v_exp_f32 — scores are bounded here, no range fixup needed
#if __has_builtin(__builtin_amdgcn_exp2f)
__device__ __forceinline__ float fexp2(float x) { return __builtin_amdgcn_exp2f(x); }
#else
__device__ __forceinline__ float fexp2(float x) { return exp2f(x); }
#endif
__device__ __forceinline__ f32x4 mfma16(short8 a, short8 b, f32x4 c) {
  return __builtin_amdgcn_mfma_f32_16x16x32_bf16(a, b, c, 0, 0, 0);
}
__device__ __forceinline__ void async16(const void* g, void* l) {
  __builtin_amdgcn_global_load_lds((__attribute__((address_space(1))) void*)g,
                                   (__attribute__((address_space(3))) void*)l,
                                   16, 0, 0);
}

// ---------------- fused cast kernel ----------------
__global__ __launch_bounds__(256) void cast_all(const float* __restrict__ hs,
                                                const float* __restrict__ Wq,
                                                const float* __restrict__ Wk,
                                                const float* __restrict__ Wv,
                                                const float* __restrict__ Wo,
                                                u16* __restrict__ dstW,
                                                u16* __restrict__ dstX) {
  int bid = blockIdx.x;
  if (bid < 4096) {
    int gid = bid * 256 + threadIdx.x;
    int wsel = gid >> 18;
    int off  = (gid & 262143) * 4;
    const float* src = (wsel == 0) ? Wq : (wsel == 1) ? Wk : (wsel == 2) ? Wv : Wo;
    float scl = (wsel == 0) ? 0.18033688f : 1.0f;   // 1/sqrt(64)*log2(e) folded into Wq
    f32x4 v = *(const f32x4*)(src + off);
    u16x4 o; o.x = f2bf(v.x * scl); o.y = f2bf(v.y * scl);
    o.z = f2bf(v.z * scl); o.w = f2bf(v.w * scl);
    *(u16x4*)(dstW + (size_t)wsel * 1048576 + off) = o;
  } else {
    int gid = (bid - 4096) * 256 + threadIdx.x;
    int e = gid * 4;
    int m = e >> 10, col = e & 1023;
    int b = m >> 11, sm = m & 2047;
    const float* src = hs + ((size_t)(b * S_ + 2 * sm) << 10) + col;
    f32x4 v = *(const f32x4*)src;
    u16x4 o; o.x = f2bf(v.x); o.y = f2bf(v.y); o.z = f2bf(v.z); o.w = f2bf(v.w);
    *(u16x4*)(dstX + ((size_t)m << 10) + col) = o;
  }
}

// ---------------- shared 128x128 double-buffered GEMM body (K=1024, B^T) ----------------
__device__ __forceinline__ void gemm_body128(const u16* __restrict__ A,
                                             const u16* __restrict__ B,
                                             u16* __restrict__ C, int N,
                                             int bm, int bn, char* lA, char* lB) {
  const int tid = threadIdx.x, lane = tid & 63, w = tid >> 6;
  const int quad = lane >> 4, l15 = lane & 15;
  const int wm = (w & 1) * 64, wn = (w >> 1) * 64;
  f32x4 acc[4][4] = {};

  auto stage = [&](int buf, int k0) {
#pragma unroll
    for (int i = 0; i < 2; i++) {
      int p = i * 256 + tid;
      int row = p >> 2, cp = p & 3;
      int c = cp ^ ((row ^ (row >> 2)) & 3);
      async16(A + (size_t)(bm + row) * 1024 + k0 + c * 8,
              lA + buf * 8192 + i * 4096 + w * 1024);
      async16(B + (size_t)(bn + row) * 1024 + k0 + c * 8,
              lB + buf * 8192 + i * 4096 + w * 1024);
    }
  };

  stage(0, 0);
#pragma unroll 1
  for (int kt = 0; kt < 32; kt++) {
    __syncthreads();
    if (kt + 1 < 32) stage((kt + 1) & 1, (kt + 1) * 32);
    const char* A_ = lA + (kt & 1) * 8192;
    const char* B_ = lB + (kt & 1) * 8192;
    short8 af[4], bf[4];
#pragma unroll
    for (int mi = 0; mi < 4; mi++) {
      int row = wm + mi * 16 + l15;
      af[mi] = *(const short8*)(A_ + (row * 4 + (quad ^ ((row ^ (row >> 2)) & 3))) * 16);
    }
#pragma unroll
    for (int ni = 0; ni < 4; ni++) {
      int row = wn + ni * 16 + l15;
      bf[ni] = *(const short8*)(B_ + (row * 4 + (quad ^ ((row ^ (row >> 2)) & 3))) * 16);
    }
#pragma unroll
    for (int mi = 0; mi < 4; mi++)
#pragma unroll
      for (int ni = 0; ni < 4; ni++)
        acc[mi][ni] = mfma16(af[mi], bf[ni], acc[mi][ni]);
  }
#pragma unroll
  for (int mi = 0; mi < 4; mi++)
#pragma unroll
    for (int ni = 0; ni < 4; ni++) {
      int m0 = bm + wm + mi * 16 + quad * 4;
      int n = bn + wn + ni * 16 + l15;
#pragma unroll
      for (int r = 0; r < 4; r++)
        C[(size_t)(m0 + r) * N + n] = f2bf(acc[mi][ni][r]);
    }
}

// fused QKV projection: blocks 0..511 -> QK = X @ [Wq;Wk]^T (M=4096,N=2048)
//                       blocks 512..767 -> Vt = Wv @ X^T    (M=1024,N=4096)
__global__ __launch_bounds__(256) void qkv_gemm(const u16* __restrict__ X,
                                                const u16* __restrict__ Wbf,
                                                u16* __restrict__ QK,
                                                u16* __restrict__ Vt) {
  __shared__ __align__(16) char lA[16384];
  __shared__ __align__(16) char lB[16384];
  int bid = blockIdx.x;
  if (bid < 512) {
    gemm_body128(X, Wbf, QK, 2048, (bid >> 4) * 128, (bid & 15) * 128, lA, lB);
  } else {
    int b2 = bid - 512;
    gemm_body128(Wbf + 2 * 1048576, X, Vt, 4096, (b2 >> 5) * 128, (b2 & 31) * 128, lA, lB);
  }
}

// ---------------- O-projection, BM=64 x BN=64 (1024 blocks, 16KB LDS) ----------------
__global__ __launch_bounds__(256) void oproj(const u16* __restrict__ A,
                                             const u16* __restrict__ B,
                                             const float* __restrict__ bo,
                                             float* __restrict__ out) {
  __shared__ __align__(16) char lA[8192];    // 2 x 4KB
  __shared__ __align__(16) char lB[8192];    // 2 x 4KB
  const int tid = threadIdx.x, lane = tid & 63, w = tid >> 6;
  const int quad = lane >> 4, l15 = lane & 15;
  const int bm = blockIdx.y * 64, bn = blockIdx.x * 64;
  const int wm = (w & 1) * 32, wn = (w >> 1) * 32;
  f32x4 acc[2][2] = {};

  auto stage = [&](int buf, int k0) {
    int row = tid >> 2, cp = tid & 3;
    int c = cp ^ ((row ^ (row >> 2)) & 3);
    async16(A + (size_t)(bm + row) * 1024 + k0 + c * 8, lA + buf * 4096 + w * 1024);
    async16(B + (size_t)(bn + row) * 1024 + k0 + c * 8, lB + buf * 4096 + w * 1024);
  };

  stage(0, 0);
#pragma unroll 1
  for (int kt = 0; kt < 32; kt++) {
    __syncthreads();
    if (kt + 1 < 32) stage((kt + 1) & 1, (kt + 1) * 32);
    const char* A_ = lA + (kt & 1) * 4096;
    const char* B_ = lB + (kt & 1) * 4096;
    short8 af[2], bf[2];
#pragma unroll
    for (int mi = 0; mi < 2; mi++) {
      int row = wm + mi * 16 + l15;
      af[mi] = *(const short8*)(A_ + (row * 4 + (quad ^ ((row ^ (row >> 2)) & 3))) * 16);
    }
#pragma unroll
    for (int ni = 0; ni < 2; ni++) {
      int row = wn + ni * 16 + l15;
      bf[ni] = *(const short8*)(B_ + (row * 4 + (quad ^ ((row ^ (row >> 2)) & 3))) * 16);
    }
#pragma unroll
    for (int mi = 0; mi < 2; mi++)
#pragma unroll
      for (int ni = 0; ni < 2; ni++)
        acc[mi][ni] = mfma16(af[mi], bf[ni], acc[mi][ni]);
  }
#pragma unroll
  for (int mi = 0; mi < 2; mi++)
#pragma unroll
    for (int ni = 0; ni < 2; ni++) {
      int n = bn + wn + ni * 16 + l15;
      float bias = bo[n];
#pragma unroll
      for (int r = 0; r < 4; r++) {
        int m = bm + wm + mi * 16 + quad * 4 + r;   // m = b*2048 + sm
        int bb = m >> 11, sm = m & 2047;
        size_t grow = ((size_t)(bb * S_ + 2 * sm)) << 10;
        out[grow + n] = acc[mi][ni][r] + bias;
        out[grow + 1024 + n] = bias;                // odd row = bo only
      }
    }
}

// ---------------- flash attention v7: 2 waves x 2 q-strips (32 q per wave) ----------------
// Each wave reads K/V fragments ONCE and uses them for two 16-q B-fragments:
// LDS fragment traffic per block-iter halves vs the 4-wave version, and the two
// independent strips give intra-wave ILP. Block = 128 threads, grid = 1024 blocks.
// Same kappa key-permutation trick as v6 (P never touches LDS).
#define VSTR 144   // V LDS row stride (bytes): 16B-aligned, spreads bank groups
__global__ __launch_bounds__(128) void attn7(const u16* __restrict__ QK,
                                             const u16* __restrict__ Vt,
                                             u16* __restrict__ O) {
  __shared__ __align__(16) char lK[2][8192];
  __shared__ __align__(16) char lV[2][64 * VSTR];
  const int tid = threadIdx.x, lane = tid & 63, w = tid >> 6;   // w in {0,1}
  const int quad = lane >> 4, l15 = lane & 15;
  const int h = blockIdx.x, b = blockIdx.y;
  const int qt = 31 - (int)blockIdx.z;        // longest blocks dispatched first
  const int qb = qt * 64;

  // Q fragments for the wave's two strips: q = qb + s*32 + w*16 + l15
  short8 qf0[2], qf1[2];
#pragma unroll
  for (int s = 0; s < 2; s++) {
    const u16* qp = QK + (size_t)(b * SD + qb + s * 32 + w * 16 + l15) * 2048 + h * 64 + quad * 8;
    qf0[s] = *(const short8*)qp;
    qf1[s] = *(const short8*)(qp + 32);
  }

  auto stageK = [&](int buf, int kb) {
#pragma unroll
    for (int i = 0; i < 4; i++) {
      int p = i * 128 + tid;                 // linear 16B-chunk position 0..511
      int row = p >> 3, c = (p & 7) ^ (row & 7);
      async16(QK + (size_t)(b * SD + kb + row) * 2048 + 1024 + h * 64 + c * 8,
              lK[buf] + i * 2048 + w * 1024);
    }
  };

  // ---- V staging (kappa-permuted): thread -> dim row vd = tid>>1, half = tid&1 ----
  const int vd = tid >> 1, half = tid & 1;
  const int vs = vd & 7;
  const u16* vgbase = Vt + (size_t)(h * 64 + vd) * 4096 + b * SD;
  u32x4 q0, q1, q2, q3;
  auto loadV = [&](int kb) {
    q0 = *(const u32x4*)(vgbase + kb + half * 16);        // keys half*16..+7
    q1 = *(const u32x4*)(vgbase + kb + half * 16 + 8);    // keys half*16+8..+15
    q2 = *(const u32x4*)(vgbase + kb + 32 + half * 16);   // +32 keys
    q3 = *(const u32x4*)(vgbase + kb + 32 + half * 16 + 8);
  };
  auto writeV = [&](int buf) {
    char* Vn = lV[buf] + vd * VSTR + half * 8;
    *(u32x2*)(Vn + ((0 ^ vs) * 16)) = u32x2{q0.x, q0.y};
    *(u32x2*)(Vn + ((1 ^ vs) * 16)) = u32x2{q0.z, q0.w};
    *(u32x2*)(Vn + ((2 ^ vs) * 16)) = u32x2{q1.x, q1.y};
    *(u32x2*)(Vn + ((3 ^ vs) * 16)) = u32x2{q1.z, q1.w};
    *(u32x2*)(Vn + ((4 ^ vs) * 16)) = u32x2{q2.x, q2.y};
    *(u32x2*)(Vn + ((5 ^ vs) * 16)) = u32x2{q2.z, q2.w};
    *(u32x2*)(Vn + ((6 ^ vs) * 16)) = u32x2{q3.x, q3.y};
    *(u32x2*)(Vn + ((7 ^ vs) * 16)) = u32x2{q3.z, q3.w};
  };

  f32x4 oacc[2][4] = {};
  float l4[2][4] = {};

  stageK(0, 0);
  loadV(0);
  writeV(0);

#pragma unroll 1
  for (int kt = 0; kt <= qt; kt++) {
    __syncthreads();                    // drains K DMA + V ds_writes for this tile
    if (kt + 1 <= qt) {
      stageK((kt + 1) & 1, (kt + 1) * 64);
      loadV((kt + 1) * 64);             // global->reg; written to LDS at end of body
    }
    const char* K_ = lK[kt & 1];
    const char* V_ = lV[kt & 1];

    // S^T = K Q^T for both strips; K fragments read once, used twice
    f32x4 s[2][4];
#pragma unroll
    for (int m = 0; m < 4; m++) {
      int key = m * 16 + l15;
      short8 kf0 = *(const short8*)(K_ + (key * 8 + (quad ^ (key & 7))) * 16);
      short8 kf1 = *(const short8*)(K_ + (key * 8 + ((4 + quad) ^ (key & 7))) * 16);
#pragma unroll
      for (int st = 0; st < 2; st++) {
        f32x4 a = {};
        a = mfma16(kf0, qf0[st], a);
        a = mfma16(kf1, qf1[st], a);
        s[st][m] = a;
      }
    }
    // causal mask: only the diagonal tile
    if (kt == qt) {
#pragma unroll
      for (int st = 0; st < 2; st++) {
        int qrel = st * 32 + w * 16 + l15;
#pragma unroll
        for (int m = 0; m < 4; m++)
#pragma unroll
          for (int r = 0; r < 4; r++)
            if (m * 16 + quad * 4 + r > qrel) s[st][m][r] = -1e30f;
      }
    }
    // fixed-max softmax + in-register kappa pack (no LDS round-trip)
    short8 pf0[2], pf1[2];
#pragma unroll
    for (int st = 0; st < 2; st++) {
      float pr[4][4];
#pragma unroll
      for (int m = 0; m < 4; m++) {
#pragma unroll
        for (int r = 0; r < 4; r++) pr[m][r] = fexp2(s[st][m][r]);
        l4[st][m] += (pr[m][0] + pr[m][1]) + (pr[m][2] + pr[m][3]);
      }
      u32 pw[8];
#pragma unroll
      for (int m = 0; m < 4; m++) {
        pw[m * 2]     = pkbf(pr[m][0], pr[m][1]);
        pw[m * 2 + 1] = pkbf(pr[m][2], pr[m][3]);
      }
      __builtin_memcpy(&pf0[st], &pw[0], 16);
      __builtin_memcpy(&pf1[st], &pw[4], 16);
    }

    // O^T += V^T P^T ; V fragments read once, used for both strips
#pragma unroll
    for (int m = 0; m < 4; m++) {
      int dr = m * 16 + l15;
      short8 vf0 = *(const short8*)(V_ + dr * VSTR + ((quad       ^ (dr & 7)) * 16));
      short8 vf1 = *(const short8*)(V_ + dr * VSTR + (((4 + quad) ^ (dr & 7)) * 16));
#pragma unroll
      for (int st = 0; st < 2; st++) {
        oacc[st][m] = mfma16(vf0, pf0[st], oacc[st][m]);
        oacc[st][m] = mfma16(vf1, pf1[st], oacc[st][m]);
      }
    }
    // write next V tile into the other LDS buffer (after its global loads land)
    if (kt + 1 <= qt) writeV((kt + 1) & 1);
  }

  // epilogue per strip: reduce l across quads, normalize, store
#pragma unroll
  for (int st = 0; st < 2; st++) {
    float l = (l4[st][0] + l4[st][1]) + (l4[st][2] + l4[st][3]);
    l += __shfl_xor(l, 16, 64);
    l += __shfl_xor(l, 32, 64);
    float inv = 1.0f / l;
    u16* op = O + (size_t)(b * SD + qb + st * 32 + w * 16 + l15) * 1024 + h * 64;
#pragma unroll
    for (int m = 0; m < 4; m++) {
      u16x4 ov;
#pragma unroll
      for (int r = 0; r < 4; r++) ov[r] = f2bf(oacc[st][m][r] * inv);
      *(u16x4*)(op + m * 16 + quad * 4) = ov;
    }
  }
}

// ---------------- host ----------------
extern "C" void kernel_launch(void* const* d_in, const int* in_sizes, int n_in,
                              void* d_out, int out_size, void* d_ws, size_t ws_size,
                              hipStream_t stream) {
  (void)in_sizes; (void)n_in; (void)out_size; (void)ws_size;
  const float* hs = (const float*)d_in[0];
  const float* Wq = (const float*)d_in[1];
  const float* Wk = (const float*)d_in[2];
  const float* Wv = (const float*)d_in[3];
  const float* Wo = (const float*)d_in[4];
  const float* bo = (const float*)d_in[5];
  float* out = (float*)d_out;
  char* ws = (char*)d_ws;

  u16* Xbf = (u16*)ws;                            // [4096][1024] even-row hs, bf16
  u16* Wbf = (u16*)(ws + (8u << 20));             // 4 x [1024][1024] bf16 (q,k,v,o)
  u16* QKb = (u16*)(ws + (16u << 20));            // [4096][2048]  Q | K fused
  u16* Vtb = (u16*)(ws + (32u << 20));            // [1024][4096]  V transposed
  u16* Ob  = (u16*)(ws + (40u << 20));            // [4096][1024]  attn out

  cast_all<<<8192, 256, 0, stream>>>(hs, Wq, Wk, Wv, Wo, Wbf, Xbf);
  qkv_gemm<<<768, 256, 0, stream>>>(Xbf, Wbf, QKb, Vtb);
  attn7<<<dim3(16, 2, 32), 128, 0, stream>>>(QKb, Vtb, Ob);
  oproj<<<dim3(16, 64), 256, 0, stream>>>(Ob, Wbf + 3 * 1048576, bo, out);
}

// Round 8
// 190.363 us; speedup vs baseline: 1.0482x; 1.0482x over previous
//
#include <hip/hip_runtime.h>
#include <cstdint>

typedef unsigned short u16;
typedef unsigned int u32;
typedef __attribute__((ext_vector_type(8))) short short8;   // 8 x bf16 bits
typedef __attribute__((ext_vector_type(4))) float f32x4;
typedef __attribute__((ext_vector_type(4))) unsigned short u16x4;
typedef __attribute__((ext_vector_type(4))) u32 u32x4;
typedef __attribute__((ext_vector_type(2))) u32 u32x2;

#define S_ 4096
#define SD 2048

__device__ __forceinline__ u16 f2bf(float f) {
  union { float f; u32 u; } v; v.f = f;
  u32 r = v.u + 0x7fffu + ((v.u >> 16) & 1u);
  return (u16)(r >> 16);
}
#if __has_builtin(__builtin_amdgcn_cvt_pk_bf16_f32)
__device__ __forceinline__ u32 pkbf(float a, float b) {
  auto r = __builtin_amdgcn_cvt_pk_bf16_f32(a, b);
  u32 o; __builtin_memcpy(&o, &r, 4); return o;
}
#else
__device__ __forceinline__ u32 pkbf(float a, float b) {
  union { float f; u32 u; } ua, ub; ua.f = a; ub.f = b;
  return __builtin_amdgcn_perm(ub.u + 0x8000u, ua.u + 0x8000u, 0x07060302u);
}
#endif
__device__ __forceinline__ f32x4 mfma16(short8 a, short8 b, f32x4 c) {
  return __builtin_amdgcn_mfma_f32_16x16x32_bf16(a, b, c, 0, 0, 0);
}
__device__ __forceinline__ void async16(const void* g, void* l) {
  __builtin_amdgcn_global_load_lds((__attribute__((address_space(1))) void*)g,
                                   (__attribute__((address_space(3))) void*)l,
                                   16, 0, 0);
}

// ---------------- fused cast kernel ----------------
__global__ __launch_bounds__(256) void cast_all(const float* __restrict__ hs,
                                                const float* __restrict__ Wq,
                                                const float* __restrict__ Wk,
                                                const float* __restrict__ Wv,
                                                const float* __restrict__ Wo,
                                                u16* __restrict__ dstW,
                                                u16* __restrict__ dstX) {
  int bid = blockIdx.x;
  if (bid < 4096) {
    int gid = bid * 256 + threadIdx.x;
    int wsel = gid >> 18;
    int off  = (gid & 262143) * 4;
    const float* src = (wsel == 0) ? Wq : (wsel == 1) ? Wk : (wsel == 2) ? Wv : Wo;
    float scl = (wsel == 0) ? 0.18033688f : 1.0f;   // 1/sqrt(64)*log2(e) folded into Wq
    f32x4 v = *(const f32x4*)(src + off);
    u16x4 o; o.x = f2bf(v.x * scl); o.y = f2bf(v.y * scl);
    o.z = f2bf(v.z * scl); o.w = f2bf(v.w * scl);
    *(u16x4*)(dstW + (size_t)wsel * 1048576 + off) = o;
  } else {
    int gid = (bid - 4096) * 256 + threadIdx.x;
    int e = gid * 4;
    int m = e >> 10, col = e & 1023;
    int b = m >> 11, sm = m & 2047;
    const float* src = hs + ((size_t)(b * S_ + 2 * sm) << 10) + col;
    f32x4 v = *(const f32x4*)src;
    u16x4 o; o.x = f2bf(v.x); o.y = f2bf(v.y); o.z = f2bf(v.z); o.w = f2bf(v.w);
    *(u16x4*)(dstX + ((size_t)m << 10) + col) = o;
  }
}

// ---------------- shared 128x128 double-buffered GEMM body (K=1024, B^T) ----------------
__device__ __forceinline__ void gemm_body128(const u16* __restrict__ A,
                                             const u16* __restrict__ B,
                                             u16* __restrict__ C, int N,
                                             int bm, int bn, char* lA, char* lB) {
  const int tid = threadIdx.x, lane = tid & 63, w = tid >> 6;
  const int quad = lane >> 4, l15 = lane & 15;
  const int wm = (w & 1) * 64, wn = (w >> 1) * 64;
  f32x4 acc[4][4] = {};

  auto stage = [&](int buf, int k0) {
#pragma unroll
    for (int i = 0; i < 2; i++) {
      int p = i * 256 + tid;
      int row = p >> 2, cp = p & 3;
      int c = cp ^ ((row ^ (row >> 2)) & 3);
      async16(A + (size_t)(bm + row) * 1024 + k0 + c * 8,
              lA + buf * 8192 + i * 4096 + w * 1024);
      async16(B + (size_t)(bn + row) * 1024 + k0 + c * 8,
              lB + buf * 8192 + i * 4096 + w * 1024);
    }
  };

  stage(0, 0);
#pragma unroll 1
  for (int kt = 0; kt < 32; kt++) {
    __syncthreads();
    if (kt + 1 < 32) stage((kt + 1) & 1, (kt + 1) * 32);
    const char* A_ = lA + (kt & 1) * 8192;
    const char* B_ = lB + (kt & 1) * 8192;
    short8 af[4], bf[4];
#pragma unroll
    for (int mi = 0; mi < 4; mi++) {
      int row = wm + mi * 16 + l15;
      af[mi] = *(const short8*)(A_ + (row * 4 + (quad ^ ((row ^ (row >> 2)) & 3))) * 16);
    }
#pragma unroll
    for (int ni = 0; ni < 4; ni++) {
      int row = wn + ni * 16 + l15;
      bf[ni] = *(const short8*)(B_ + (row * 4 + (quad ^ ((row ^ (row >> 2)) & 3))) * 16);
    }
#pragma unroll
    for (int mi = 0; mi < 4; mi++)
#pragma unroll
      for (int ni = 0; ni < 4; ni++)
        acc[mi][ni] = mfma16(af[mi], bf[ni], acc[mi][ni]);
  }
#pragma unroll
  for (int mi = 0; mi < 4; mi++)
#pragma unroll
    for (int ni = 0; ni < 4; ni++) {
      int m0 = bm + wm + mi * 16 + quad * 4;
      int n = bn + wn + ni * 16 + l15;
#pragma unroll
      for (int r = 0; r < 4; r++)
        C[(size_t)(m0 + r) * N + n] = f2bf(acc[mi][ni][r]);
    }
}

// fused QKV projection: blocks 0..511 -> QK = X @ [Wq;Wk]^T (M=4096,N=2048)
//                       blocks 512..767 -> Vt = Wv @ X^T    (M=1024,N=4096)
__global__ __launch_bounds__(256) void qkv_gemm(const u16* __restrict__ X,
                                                const u16* __restrict__ Wbf,
                                                u16* __restrict__ QK,
                                                u16* __restrict__ Vt) {
  __shared__ __align__(16) char lA[16384];
  __shared__ __align__(16) char lB[16384];
  int bid = blockIdx.x;
  if (bid < 512) {
    gemm_body128(X, Wbf, QK, 2048, (bid >> 4) * 128, (bid & 15) * 128, lA, lB);
  } else {
    int b2 = bid - 512;
    gemm_body128(Wbf + 2 * 1048576, X, Vt, 4096, (b2 >> 5) * 128, (b2 & 31) * 128, lA, lB);
  }
}

// ---------------- O-projection: BM=64 x BN=128, wave 32x64 (512 blocks, 24KB) ----------------
// 6 ds_read_b128 per 8 MFMA per wave-iter, 64 block-iters/CU (vs 128 at BN=64).
__global__ __launch_bounds__(256) void oproj(const u16* __restrict__ A,
                                             const u16* __restrict__ B,
                                             const float* __restrict__ bo,
                                             float* __restrict__ out) {
  __shared__ __align__(16) char lA[8192];    // 2 x 4KB
  __shared__ __align__(16) char lB[16384];   // 2 x 8KB
  const int tid = threadIdx.x, lane = tid & 63, w = tid >> 6;
  const int quad = lane >> 4, l15 = lane & 15;
  const int bm = blockIdx.y * 64, bn = blockIdx.x * 128;
  const int wm = (w & 1) * 32, wn = (w >> 1) * 64;
  f32x4 acc[2][4] = {};

  auto stage = [&](int buf, int k0) {
    {
      int row = tid >> 2, cp = tid & 3;
      int c = cp ^ ((row ^ (row >> 2)) & 3);
      async16(A + (size_t)(bm + row) * 1024 + k0 + c * 8, lA + buf * 4096 + w * 1024);
    }
#pragma unroll
    for (int i = 0; i < 2; i++) {
      int p = i * 256 + tid;
      int row = p >> 2, cp = p & 3;
      int c = cp ^ ((row ^ (row >> 2)) & 3);
      async16(B + (size_t)(bn + row) * 1024 + k0 + c * 8, lB + buf * 8192 + i * 4096 + w * 1024);
    }
  };

  stage(0, 0);
#pragma unroll 1
  for (int kt = 0; kt < 32; kt++) {
    __syncthreads();
    if (kt + 1 < 32) stage((kt + 1) & 1, (kt + 1) * 32);
    const char* A_ = lA + (kt & 1) * 4096;
    const char* B_ = lB + (kt & 1) * 8192;
    short8 af[2], bf[4];
#pragma unroll
    for (int mi = 0; mi < 2; mi++) {
      int row = wm + mi * 16 + l15;
      af[mi] = *(const short8*)(A_ + (row * 4 + (quad ^ ((row ^ (row >> 2)) & 3))) * 16);
    }
#pragma unroll
    for (int ni = 0; ni < 4; ni++) {
      int row = wn + ni * 16 + l15;
      bf[ni] = *(const short8*)(B_ + (row * 4 + (quad ^ ((row ^ (row >> 2)) & 3))) * 16);
    }
#pragma unroll
    for (int mi = 0; mi < 2; mi++)
#pragma unroll
      for (int ni = 0; ni < 4; ni++)
        acc[mi][ni] = mfma16(af[mi], bf[ni], acc[mi][ni]);
  }
#pragma unroll
  for (int mi = 0; mi < 2; mi++)
#pragma unroll
    for (int ni = 0; ni < 4; ni++) {
      int n = bn + wn + ni * 16 + l15;
      float bias = bo[n];
#pragma unroll
      for (int r = 0; r < 4; r++) {
        int m = bm + wm + mi * 16 + quad * 4 + r;   // m = b*2048 + sm
        int bb = m >> 11, sm = m & 2047;
        size_t grow = ((size_t)(bb * S_ + 2 * sm)) << 10;
        out[grow + n] = acc[mi][ni][r] + bias;
        out[grow + 1024 + n] = bias;                // odd row = bo only
      }
    }
}

// ---------------- flash attention v6 (proven 50.3 us): kappa-permuted P, no LDS round-trip ----------------
// QK: [4096 tok][2048] bf16 (cols 0..1023 = Q pre-scaled to log2 domain, 1024..2047 = K).
// Vt: [1024][4096] bf16 (row = h*64+d, col = b*2048+s).  O: [4096][1024] bf16.
__global__ __launch_bounds__(256) void attn6(const u16* __restrict__ QK,
                                             const u16* __restrict__ Vt,
                                             u16* __restrict__ O) {
  __shared__ __align__(16) char lK[2][8192];
  __shared__ __align__(16) char lV[2][8192];
  const int tid = threadIdx.x, lane = tid & 63, w = tid >> 6;
  const int quad = lane >> 4, l15 = lane & 15;
  const int h = blockIdx.x, b = blockIdx.y;
  const int qt = 31 - (int)blockIdx.z;        // longest blocks dispatched first
  const int qb = qt * 64 + w * 16;

  const u16* qp = QK + (size_t)(b * SD + qb + l15) * 2048 + h * 64 + quad * 8;
  short8 qf0 = *(const short8*)qp;
  short8 qf1 = *(const short8*)(qp + 32);

  auto stageK = [&](int buf, int kb) {
#pragma unroll
    for (int i = 0; i < 2; i++) {
      int p = (w * 2 + i) * 64 + lane;
      int row = p >> 3, c = (p & 7) ^ (row & 7);
      async16(QK + (size_t)(b * SD + kb + row) * 2048 + 1024 + h * 64 + c * 8,
              lK[buf] + (w * 2 + i) * 1024);
    }
  };

  // ---- V staging (kappa-permuted): thread -> dim row vd, global pieces vg and vg+4 ----
  const int vd = tid >> 2, vg = tid & 3;
  const u16* vgbase = Vt + (size_t)(h * 64 + vd) * 4096 + b * SD;
  const int vs = vd & 7;
  const int cb0 = (vg & 1) * 2;
  const int cb1 = cb0 + 4;
  const int inn = (vg >> 1) * 8;
  const int aw0 = vd * 128 + ((cb0     ^ vs) * 16) + inn;
  const int aw1 = vd * 128 + (((cb0+1) ^ vs) * 16) + inn;
  const int aw2 = vd * 128 + ((cb1     ^ vs) * 16) + inn;
  const int aw3 = vd * 128 + (((cb1+1) ^ vs) * 16) + inn;

  u32x4 nv0, nv1;
  auto loadV = [&](int kb) {
    nv0 = *(const u32x4*)(vgbase + kb + vg * 8);
    nv1 = *(const u32x4*)(vgbase + kb + 32 + vg * 8);
  };
  auto writeV = [&](int buf) {
    char* Vn = lV[buf];
    *(u32x2*)(Vn + aw0) = u32x2{nv0.x, nv0.y};
    *(u32x2*)(Vn + aw1) = u32x2{nv0.z, nv0.w};
    *(u32x2*)(Vn + aw2) = u32x2{nv1.x, nv1.y};
    *(u32x2*)(Vn + aw3) = u32x2{nv1.z, nv1.w};
  };

  f32x4 oacc[4] = {};
  float l4[4] = {0.f, 0.f, 0.f, 0.f};

  stageK(0, 0);
  loadV(0);
  writeV(0);

#pragma unroll 1
  for (int kt = 0; kt <= qt; kt++) {
    __syncthreads();
    if (kt + 1 <= qt) {
      stageK((kt + 1) & 1, (kt + 1) * 64);
      loadV((kt + 1) * 64);
    }
    const char* K_ = lK[kt & 1];
    const char* V_ = lV[kt & 1];

    // S^T = K Q^T
    f32x4 s[4];
#pragma unroll
    for (int m = 0; m < 4; m++) {
      int key = m * 16 + l15;
      short8 kf0 = *(const short8*)(K_ + (key * 8 + (quad ^ (key & 7))) * 16);
      short8 kf1 = *(const short8*)(K_ + (key * 8 + ((4 + quad) ^ (key & 7))) * 16);
      f32x4 a = {};
      a = mfma16(kf0, qf0, a);
      a = mfma16(kf1, qf1, a);
      s[m] = a;
    }
    if (kt == qt) {
      int qrel = w * 16 + l15;
#pragma unroll
      for (int m = 0; m < 4; m++)
#pragma unroll
        for (int r = 0; r < 4; r++)
          if (m * 16 + quad * 4 + r > qrel) s[m][r] = -1e30f;
    }
    float pr[4][4];
#pragma unroll
    for (int m = 0; m < 4; m++) {
#pragma unroll
      for (int r = 0; r < 4; r++) pr[m][r] = exp2f(s[m][r]);
      l4[m] += (pr[m][0] + pr[m][1]) + (pr[m][2] + pr[m][3]);
    }
    u32 pw[8];
#pragma unroll
    for (int m = 0; m < 4; m++) {
      pw[m * 2]     = pkbf(pr[m][0], pr[m][1]);
      pw[m * 2 + 1] = pkbf(pr[m][2], pr[m][3]);
    }
    short8 pf0, pf1;
    __builtin_memcpy(&pf0, &pw[0], 16);
    __builtin_memcpy(&pf1, &pw[4], 16);

#pragma unroll
    for (int m = 0; m < 4; m++) {
      int dr = m * 16 + l15;
      short8 vf0 = *(const short8*)(V_ + (dr * 128 + ((quad     ^ (dr & 7)) * 16)));
      short8 vf1 = *(const short8*)(V_ + (dr * 128 + (((4+quad) ^ (dr & 7)) * 16)));
      oacc[m] = mfma16(vf0, pf0, oacc[m]);
      oacc[m] = mfma16(vf1, pf1, oacc[m]);
    }
    if (kt + 1 <= qt) writeV((kt + 1) & 1);
  }

  float l = (l4[0] + l4[1]) + (l4[2] + l4[3]);
  l += __shfl_xor(l, 16, 64);
  l += __shfl_xor(l, 32, 64);
  float inv = 1.0f / l;
  u16* op = O + (size_t)(b * SD + qb + l15) * 1024 + h * 64;
#pragma unroll
  for (int m = 0; m < 4; m++) {
    u16x4 ov;
#pragma unroll
    for (int r = 0; r < 4; r++) ov[r] = f2bf(oacc[m][r] * inv);
    *(u16x4*)(op + m * 16 + quad * 4) = ov;
  }
}

// ---------------- host ----------------
extern "C" void kernel_launch(void* const* d_in, const int* in_sizes, int n_in,
                              void* d_out, int out_size, void* d_ws, size_t ws_size,
                              hipStream_t stream) {
  (void)in_sizes; (void)n_in; (void)out_size; (void)ws_size;
  const float* hs = (const float*)d_in[0];
  const float* Wq = (const float*)d_in[1];
  const float* Wk = (const float*)d_in[2];
  const float* Wv = (const float*)d_in[3];
  const float* Wo = (const float*)d_in[4];
  const float* bo = (const float*)d_in[5];
  float* out = (float*)d_out;
  char* ws = (char*)d_ws;

  u16* Xbf = (u16*)ws;                            // [4096][1024] even-row hs, bf16
  u16* Wbf = (u16*)(ws + (8u << 20));             // 4 x [1024][1024] bf16 (q,k,v,o)
  u16* QKb = (u16*)(ws + (16u << 20));            // [4096][2048]  Q | K fused
  u16* Vtb = (u16*)(ws + (32u << 20));            // [1024][4096]  V transposed
  u16* Ob  = (u16*)(ws + (40u << 20));            // [4096][1024]  attn out

  cast_all<<<8192, 256, 0, stream>>>(hs, Wq, Wk, Wv, Wo, Wbf, Xbf);
  qkv_gemm<<<768, 256, 0, stream>>>(Xbf, Wbf, QKb, Vtb);
  attn6<<<dim3(16, 2, 32), 256, 0, stream>>>(QKb, Vtb, Ob);
  oproj<<<dim3(8, 64), 256, 0, stream>>>(Ob, Wbf + 3 * 1048576, bo, out);
}